// Round 1
// baseline (831.582 us; speedup 1.0000x reference)
//
#include <hip/hip_runtime.h>

#define V_N 100000
#define C_N 50000
#define E_N 1250000
#define VF_N 32
#define H_N 64
#define ROUNDS 3
#define SCAN_CHUNK 4096

// ---------------- CSR build ----------------

__global__ __launch_bounds__(256) void hist_k(const int* __restrict__ vi,
                                              const int* __restrict__ ci,
                                              int* __restrict__ cnt_c,
                                              int* __restrict__ cnt_v) {
  int i = blockIdx.x * 256 + threadIdx.x;
  if (i >= E_N) return;
  atomicAdd(&cnt_v[vi[i]], 1);
  atomicAdd(&cnt_c[ci[i]], 1);
}

__global__ __launch_bounds__(256) void scan_partial(const int* __restrict__ cnt, int n,
                                                    int* __restrict__ part) {
  __shared__ int lds[256];
  int base = blockIdx.x * SCAN_CHUNK;
  int t = threadIdx.x;
  int sum = 0;
  for (int i = t; i < SCAN_CHUNK; i += 256) {
    int idx = base + i;
    sum += (idx < n) ? cnt[idx] : 0;
  }
  lds[t] = sum;
  __syncthreads();
  for (int off = 128; off > 0; off >>= 1) {
    if (t < off) lds[t] += lds[t + off];
    __syncthreads();
  }
  if (t == 0) part[blockIdx.x] = lds[0];
}

__global__ __launch_bounds__(256) void scan_final(const int* __restrict__ cnt, int n,
                                                  const int* __restrict__ part, int nblocks,
                                                  int* __restrict__ rs, int* __restrict__ cur) {
  __shared__ int lds[256];
  int b = blockIdx.x, t = threadIdx.x;
  int offset = 0;
  for (int i = 0; i < b; ++i) offset += part[i];
  int base = b * SCAN_CHUNK + t * 16;
  int vals[16];
  int tot = 0;
#pragma unroll
  for (int i = 0; i < 16; ++i) {
    int idx = base + i;
    int v = (idx < n) ? cnt[idx] : 0;
    vals[i] = tot;  // exclusive within thread
    tot += v;
  }
  lds[t] = tot;
  __syncthreads();
  // Hillis-Steele inclusive scan over 256 thread totals
  for (int off = 1; off < 256; off <<= 1) {
    int v = (t >= off) ? lds[t - off] : 0;
    __syncthreads();
    lds[t] += v;
    __syncthreads();
  }
  int texcl = lds[t] - tot;
#pragma unroll
  for (int i = 0; i < 16; ++i) {
    int idx = base + i;
    if (idx < n) {
      int val = offset + texcl + vals[i];
      rs[idx] = val;
      cur[idx] = val;
    }
  }
  if (b == 0 && t == 0) {
    int g = 0;
    for (int i = 0; i < nblocks; ++i) g += part[i];
    rs[n] = g;
  }
}

__global__ __launch_bounds__(256) void fill_k(const int* __restrict__ vi,
                                              const int* __restrict__ ci,
                                              int* __restrict__ cur_c, int* __restrict__ cur_v,
                                              int* __restrict__ src_c, int* __restrict__ src_v) {
  int i = blockIdx.x * 256 + threadIdx.x;
  if (i >= E_N) return;
  int v = vi[i], c = ci[i];
  int p = atomicAdd(&cur_c[c], 1);
  src_c[p] = v;  // constraint-major CSR stores source var ids
  int q = atomicAdd(&cur_v[v], 1);
  src_v[q] = c;  // var-major CSR stores source constraint ids
}

// ---------------- input MLP: h = relu(feat[n,32] @ W[32,64] + b) ----------------

__global__ __launch_bounds__(256) void init_mlp(const float* __restrict__ feat,
                                                const float* __restrict__ W,
                                                const float* __restrict__ b,
                                                float* __restrict__ h, int n) {
  __shared__ float Wl[VF_N * H_N];
  for (int i = threadIdx.x; i < VF_N * H_N; i += 256) Wl[i] = W[i];
  __syncthreads();
  int g = (blockIdx.x * 256 + threadIdx.x) >> 4;
  int lane = threadIdx.x & 15;
  if (g >= n) return;
  float2 rv = *(const float2*)&feat[(size_t)g * VF_N + lane * 2];
  float4 acc = *(const float4*)&b[lane * 4];
#pragma unroll
  for (int k = 0; k < VF_N; ++k) {
    float el = (k & 1) ? rv.y : rv.x;
    float v = __shfl(el, k >> 1, 16);
    float4 w = *(const float4*)&Wl[k * H_N + lane * 4];
    acc.x += v * w.x; acc.y += v * w.y; acc.z += v * w.z; acc.w += v * w.w;
  }
  acc.x = fmaxf(acc.x, 0.f); acc.y = fmaxf(acc.y, 0.f);
  acc.z = fmaxf(acc.z, 0.f); acc.w = fmaxf(acc.w, 0.f);
  *(float4*)&h[(size_t)g * H_N + lane * 4] = acc;
}

// ---------------- dense: t = h[n,64] @ W[64,64]  (no bias/relu) ----------------

__global__ __launch_bounds__(256) void dense64(const float* __restrict__ in,
                                               const float* __restrict__ W,
                                               float* __restrict__ out, int n) {
  __shared__ float Wl[H_N * H_N];
  for (int i = threadIdx.x; i < H_N * H_N; i += 256) Wl[i] = W[i];
  __syncthreads();
  int g = (blockIdx.x * 256 + threadIdx.x) >> 4;
  int lane = threadIdx.x & 15;
  if (g >= n) return;
  float4 rv = *(const float4*)&in[(size_t)g * H_N + lane * 4];
  float4 acc = {0.f, 0.f, 0.f, 0.f};
#pragma unroll
  for (int k = 0; k < H_N; ++k) {
    int sel = k & 3;
    float el = (sel == 0) ? rv.x : (sel == 1) ? rv.y : (sel == 2) ? rv.z : rv.w;
    float v = __shfl(el, k >> 2, 16);
    float4 w = *(const float4*)&Wl[k * H_N + lane * 4];
    acc.x += v * w.x; acc.y += v * w.y; acc.z += v * w.z; acc.w += v * w.w;
  }
  *(float4*)&out[(size_t)g * H_N + lane * 4] = acc;
}

// ---------------- gather + residual + bias + relu ----------------
// h[d] = relu(h[d] + sum_{p in [rs[d],rs[d+1])} t[src[p]] + bias)

__global__ __launch_bounds__(256) void gather_update(const float* __restrict__ t,
                                                     const int* __restrict__ rs,
                                                     const int* __restrict__ src,
                                                     const float* __restrict__ bias,
                                                     float* __restrict__ h, int n) {
  int g = (blockIdx.x * 256 + threadIdx.x) >> 4;
  int lane = threadIdx.x & 15;
  if (g >= n) return;
  int s = rs[g], e = rs[g + 1];
  float4 acc = {0.f, 0.f, 0.f, 0.f};
  for (int p = s; p < e; p += 16) {
    int cnt = e - p;
    if (cnt > 16) cnt = 16;
    int myidx = (lane < cnt) ? src[p + lane] : 0;
    for (int j = 0; j < cnt; ++j) {
      int sj = __shfl(myidx, j, 16);
      float4 v = *(const float4*)&t[(size_t)sj * H_N + lane * 4];
      acc.x += v.x; acc.y += v.y; acc.z += v.z; acc.w += v.w;
    }
  }
  float4 hv = *(const float4*)&h[(size_t)g * H_N + lane * 4];
  float4 b4 = *(const float4*)&bias[lane * 4];
  float4 o;
  o.x = fmaxf(hv.x + acc.x + b4.x, 0.f);
  o.y = fmaxf(hv.y + acc.y + b4.y, 0.f);
  o.z = fmaxf(hv.z + acc.z + b4.z, 0.f);
  o.w = fmaxf(hv.w + acc.w + b4.w, 0.f);
  *(float4*)&h[(size_t)g * H_N + lane * 4] = o;
}

// ---------------- score: out[v] = dot(h[v], Ws) + b ----------------

__global__ __launch_bounds__(256) void score_k(const float* __restrict__ h,
                                               const float* __restrict__ Ws,
                                               const float* __restrict__ bs,
                                               float* __restrict__ out, int n) {
  int g = (blockIdx.x * 256 + threadIdx.x) >> 4;
  int lane = threadIdx.x & 15;
  if (g >= n) return;
  float4 hv = *(const float4*)&h[(size_t)g * H_N + lane * 4];
  float4 w = *(const float4*)&Ws[lane * 4];
  float d = hv.x * w.x + hv.y * w.y + hv.z * w.z + hv.w * w.w;
  d += __shfl_down(d, 8, 16);
  d += __shfl_down(d, 4, 16);
  d += __shfl_down(d, 2, 16);
  d += __shfl_down(d, 1, 16);
  if (lane == 0) out[g] = d + bs[0];
}

// ---------------- launch ----------------

extern "C" void kernel_launch(void* const* d_in, const int* in_sizes, int n_in,
                              void* d_out, int out_size, void* d_ws, size_t ws_size,
                              hipStream_t stream) {
  const float* var_feat = (const float*)d_in[0];
  const float* con_feat = (const float*)d_in[1];
  const float* W_var = (const float*)d_in[2];
  const float* b_var = (const float*)d_in[3];
  const float* W_con = (const float*)d_in[4];
  const float* b_con = (const float*)d_in[5];
  const float* W_v2c = (const float*)d_in[6];
  const float* b_v2c = (const float*)d_in[7];
  const float* W_c2v = (const float*)d_in[8];
  const float* b_c2v = (const float*)d_in[9];
  const float* W_score = (const float*)d_in[10];
  const float* b_score = (const float*)d_in[11];
  const int* var_idx = (const int*)d_in[12];
  const int* constr_idx = (const int*)d_in[13];
  float* out = (float*)d_out;

  char* p = (char*)d_ws;
  auto alloc = [&](size_t bytes) {
    char* r = p;
    p += (bytes + 255) & ~(size_t)255;
    return r;
  };
  float* h_var = (float*)alloc((size_t)V_N * H_N * 4);
  float* h_con = (float*)alloc((size_t)C_N * H_N * 4);
  float* t_buf = (float*)alloc((size_t)V_N * H_N * 4);
  int* cnt_c = (int*)alloc((size_t)C_N * 4);
  int* cnt_v = (int*)alloc((size_t)V_N * 4);
  int* rs_c = (int*)alloc((size_t)(C_N + 1) * 4);
  int* rs_v = (int*)alloc((size_t)(V_N + 1) * 4);
  int* cur_c = (int*)alloc((size_t)C_N * 4);
  int* cur_v = (int*)alloc((size_t)V_N * 4);
  int* src_c = (int*)alloc((size_t)E_N * 4);
  int* src_v = (int*)alloc((size_t)E_N * 4);
  int* part_c = (int*)alloc(64 * 4);
  int* part_v = (int*)alloc(64 * 4);

  hipMemsetAsync(cnt_c, 0, (size_t)C_N * 4, stream);
  hipMemsetAsync(cnt_v, 0, (size_t)V_N * 4, stream);

  hist_k<<<(E_N + 255) / 256, 256, 0, stream>>>(var_idx, constr_idx, cnt_c, cnt_v);

  int nb_c = (C_N + SCAN_CHUNK - 1) / SCAN_CHUNK;
  int nb_v = (V_N + SCAN_CHUNK - 1) / SCAN_CHUNK;
  scan_partial<<<nb_c, 256, 0, stream>>>(cnt_c, C_N, part_c);
  scan_partial<<<nb_v, 256, 0, stream>>>(cnt_v, V_N, part_v);
  scan_final<<<nb_c, 256, 0, stream>>>(cnt_c, C_N, part_c, nb_c, rs_c, cur_c);
  scan_final<<<nb_v, 256, 0, stream>>>(cnt_v, V_N, part_v, nb_v, rs_v, cur_v);

  fill_k<<<(E_N + 255) / 256, 256, 0, stream>>>(var_idx, constr_idx, cur_c, cur_v, src_c, src_v);

  init_mlp<<<(V_N + 15) / 16, 256, 0, stream>>>(var_feat, W_var, b_var, h_var, V_N);
  init_mlp<<<(C_N + 15) / 16, 256, 0, stream>>>(con_feat, W_con, b_con, h_con, C_N);

  for (int r = 0; r < ROUNDS; ++r) {
    // t = h_var @ W_v2c ; h_con = relu(h_con + segsum_c(t) + b_v2c)
    dense64<<<(V_N + 15) / 16, 256, 0, stream>>>(h_var, W_v2c, t_buf, V_N);
    gather_update<<<(C_N + 15) / 16, 256, 0, stream>>>(t_buf, rs_c, src_c, b_v2c, h_con, C_N);
    // t = h_con @ W_c2v ; h_var = relu(h_var + segsum_v(t) + b_c2v)
    dense64<<<(C_N + 15) / 16, 256, 0, stream>>>(h_con, W_c2v, t_buf, C_N);
    gather_update<<<(V_N + 15) / 16, 256, 0, stream>>>(t_buf, rs_v, src_v, b_c2v, h_var, V_N);
  }

  score_k<<<(V_N + 15) / 16, 256, 0, stream>>>(h_var, W_score, b_score, out, V_N);
}

// Round 2
// 789.759 us; speedup vs baseline: 1.0530x; 1.0530x over previous
//
#include <hip/hip_runtime.h>

#define V_N 100000
#define C_N 50000
#define E_N 1250000
#define VF_N 32
#define H_N 64
#define ROUNDS 3
#define SCAN_CHUNK 4096

// ---------------- CSR build: histogram + scan + linked-list + flatten ----------------

__global__ __launch_bounds__(256) void hist_k(const int* __restrict__ vi,
                                              const int* __restrict__ ci,
                                              int* __restrict__ cnt_c,
                                              int* __restrict__ cnt_v) {
  int i = blockIdx.x * 256 + threadIdx.x;
  if (i >= E_N) return;
  atomicAdd(&cnt_v[vi[i]], 1);
  atomicAdd(&cnt_c[ci[i]], 1);
}

__global__ __launch_bounds__(256) void scan_partial(const int* __restrict__ cnt, int n,
                                                    int* __restrict__ part) {
  __shared__ int lds[256];
  int base = blockIdx.x * SCAN_CHUNK;
  int t = threadIdx.x;
  int sum = 0;
  for (int i = t; i < SCAN_CHUNK; i += 256) {
    int idx = base + i;
    sum += (idx < n) ? cnt[idx] : 0;
  }
  lds[t] = sum;
  __syncthreads();
  for (int off = 128; off > 0; off >>= 1) {
    if (t < off) lds[t] += lds[t + off];
    __syncthreads();
  }
  if (t == 0) part[blockIdx.x] = lds[0];
}

__global__ __launch_bounds__(256) void scan_final(const int* __restrict__ cnt, int n,
                                                  const int* __restrict__ part, int nblocks,
                                                  int* __restrict__ rs) {
  __shared__ int lds[256];
  int b = blockIdx.x, t = threadIdx.x;
  int offset = 0;
  for (int i = 0; i < b; ++i) offset += part[i];
  int base = b * SCAN_CHUNK + t * 16;
  int vals[16];
  int tot = 0;
#pragma unroll
  for (int i = 0; i < 16; ++i) {
    int idx = base + i;
    int v = (idx < n) ? cnt[idx] : 0;
    vals[i] = tot;  // exclusive within thread
    tot += v;
  }
  lds[t] = tot;
  __syncthreads();
  for (int off = 1; off < 256; off <<= 1) {
    int v = (t >= off) ? lds[t - off] : 0;
    __syncthreads();
    lds[t] += v;
    __syncthreads();
  }
  int texcl = lds[t] - tot;
#pragma unroll
  for (int i = 0; i < 16; ++i) {
    int idx = base + i;
    if (idx < n) rs[idx] = offset + texcl + vals[i];
  }
  if (b == 0 && t == 0) {
    int g = 0;
    for (int i = 0; i < nblocks; ++i) g += part[i];
    rs[n] = g;
  }
}

// Per-destination linked lists. next_* writes are fully sequential (coalesced,
// full-line); head_* atomics hit small L2-resident arrays. This replaces the
// old fill_k whose random 4B stores cost 160MB of partial-line HBM writes.
__global__ __launch_bounds__(256) void build_list(const int* __restrict__ vi,
                                                  const int* __restrict__ ci,
                                                  int* __restrict__ head_c,
                                                  int* __restrict__ head_v,
                                                  int* __restrict__ next_c,
                                                  int* __restrict__ next_v) {
  int i = blockIdx.x * 256 + threadIdx.x;
  if (i >= E_N) return;
  next_c[i] = atomicExch(&head_c[ci[i]], i);
  next_v[i] = atomicExch(&head_v[vi[i]], i);
}

// One thread per destination: walk chain, write its CSR source list
// contiguously (per-thread sequential stores -> full-line dirty).
__global__ __launch_bounds__(256) void flatten_k(const int* __restrict__ head,
                                                 const int* __restrict__ next,
                                                 const int* __restrict__ srcids,
                                                 const int* __restrict__ rs,
                                                 int* __restrict__ out_src, int n) {
  int d = blockIdx.x * 256 + threadIdx.x;
  if (d >= n) return;
  int p = rs[d];
  int e = head[d];
  while (e >= 0) {
    out_src[p++] = srcids[e];
    e = next[e];
  }
}

// ---------------- input MLP: h = relu(feat[n,32] @ W[32,64] + b) ----------------

__global__ __launch_bounds__(256) void init_mlp(const float* __restrict__ feat,
                                                const float* __restrict__ W,
                                                const float* __restrict__ b,
                                                float* __restrict__ h, int n) {
  __shared__ float Wl[VF_N * H_N];
  for (int i = threadIdx.x; i < VF_N * H_N; i += 256) Wl[i] = W[i];
  __syncthreads();
  int g = (blockIdx.x * 256 + threadIdx.x) >> 4;
  int lane = threadIdx.x & 15;
  if (g >= n) return;
  float2 rv = *(const float2*)&feat[(size_t)g * VF_N + lane * 2];
  float4 acc = *(const float4*)&b[lane * 4];
#pragma unroll
  for (int k = 0; k < VF_N; ++k) {
    float el = (k & 1) ? rv.y : rv.x;
    float v = __shfl(el, k >> 1, 16);
    float4 w = *(const float4*)&Wl[k * H_N + lane * 4];
    acc.x += v * w.x; acc.y += v * w.y; acc.z += v * w.z; acc.w += v * w.w;
  }
  acc.x = fmaxf(acc.x, 0.f); acc.y = fmaxf(acc.y, 0.f);
  acc.z = fmaxf(acc.z, 0.f); acc.w = fmaxf(acc.w, 0.f);
  *(float4*)&h[(size_t)g * H_N + lane * 4] = acc;
}

// ---------------- dense: t = h[n,64] @ W[64,64]  (no bias/relu) ----------------

__global__ __launch_bounds__(256) void dense64(const float* __restrict__ in,
                                               const float* __restrict__ W,
                                               float* __restrict__ out, int n) {
  __shared__ float Wl[H_N * H_N];
  for (int i = threadIdx.x; i < H_N * H_N; i += 256) Wl[i] = W[i];
  __syncthreads();
  int g = (blockIdx.x * 256 + threadIdx.x) >> 4;
  int lane = threadIdx.x & 15;
  if (g >= n) return;
  float4 rv = *(const float4*)&in[(size_t)g * H_N + lane * 4];
  float4 acc = {0.f, 0.f, 0.f, 0.f};
#pragma unroll
  for (int k = 0; k < H_N; ++k) {
    int sel = k & 3;
    float el = (sel == 0) ? rv.x : (sel == 1) ? rv.y : (sel == 2) ? rv.z : rv.w;
    float v = __shfl(el, k >> 2, 16);
    float4 w = *(const float4*)&Wl[k * H_N + lane * 4];
    acc.x += v * w.x; acc.y += v * w.y; acc.z += v * w.z; acc.w += v * w.w;
  }
  *(float4*)&out[(size_t)g * H_N + lane * 4] = acc;
}

// ---------------- gather + residual + bias + relu ----------------
// h[d] = relu(h[d] + sum_{p in [rs[d],rs[d+1])} t[src[p]] + bias)

__global__ __launch_bounds__(256) void gather_update(const float* __restrict__ t,
                                                     const int* __restrict__ rs,
                                                     const int* __restrict__ src,
                                                     const float* __restrict__ bias,
                                                     float* __restrict__ h, int n) {
  int g = (blockIdx.x * 256 + threadIdx.x) >> 4;
  int lane = threadIdx.x & 15;
  if (g >= n) return;
  int s = rs[g], e = rs[g + 1];
  float4 acc = {0.f, 0.f, 0.f, 0.f};
  for (int p = s; p < e; p += 16) {
    int cnt = e - p;
    if (cnt > 16) cnt = 16;
    int myidx = (lane < cnt) ? src[p + lane] : 0;
    for (int j = 0; j < cnt; ++j) {
      int sj = __shfl(myidx, j, 16);
      float4 v = *(const float4*)&t[(size_t)sj * H_N + lane * 4];
      acc.x += v.x; acc.y += v.y; acc.z += v.z; acc.w += v.w;
    }
  }
  float4 hv = *(const float4*)&h[(size_t)g * H_N + lane * 4];
  float4 b4 = *(const float4*)&bias[lane * 4];
  float4 o;
  o.x = fmaxf(hv.x + acc.x + b4.x, 0.f);
  o.y = fmaxf(hv.y + acc.y + b4.y, 0.f);
  o.z = fmaxf(hv.z + acc.z + b4.z, 0.f);
  o.w = fmaxf(hv.w + acc.w + b4.w, 0.f);
  *(float4*)&h[(size_t)g * H_N + lane * 4] = o;
}

// ---------------- score: out[v] = dot(h[v], Ws) + b ----------------

__global__ __launch_bounds__(256) void score_k(const float* __restrict__ h,
                                               const float* __restrict__ Ws,
                                               const float* __restrict__ bs,
                                               float* __restrict__ out, int n) {
  int g = (blockIdx.x * 256 + threadIdx.x) >> 4;
  int lane = threadIdx.x & 15;
  if (g >= n) return;
  float4 hv = *(const float4*)&h[(size_t)g * H_N + lane * 4];
  float4 w = *(const float4*)&Ws[lane * 4];
  float d = hv.x * w.x + hv.y * w.y + hv.z * w.z + hv.w * w.w;
  d += __shfl_down(d, 8, 16);
  d += __shfl_down(d, 4, 16);
  d += __shfl_down(d, 2, 16);
  d += __shfl_down(d, 1, 16);
  if (lane == 0) out[g] = d + bs[0];
}

// ---------------- launch ----------------

extern "C" void kernel_launch(void* const* d_in, const int* in_sizes, int n_in,
                              void* d_out, int out_size, void* d_ws, size_t ws_size,
                              hipStream_t stream) {
  const float* var_feat = (const float*)d_in[0];
  const float* con_feat = (const float*)d_in[1];
  const float* W_var = (const float*)d_in[2];
  const float* b_var = (const float*)d_in[3];
  const float* W_con = (const float*)d_in[4];
  const float* b_con = (const float*)d_in[5];
  const float* W_v2c = (const float*)d_in[6];
  const float* b_v2c = (const float*)d_in[7];
  const float* W_c2v = (const float*)d_in[8];
  const float* b_c2v = (const float*)d_in[9];
  const float* W_score = (const float*)d_in[10];
  const float* b_score = (const float*)d_in[11];
  const int* var_idx = (const int*)d_in[12];
  const int* constr_idx = (const int*)d_in[13];
  float* out = (float*)d_out;

  char* p = (char*)d_ws;
  auto alloc = [&](size_t bytes) {
    char* r = p;
    p += (bytes + 255) & ~(size_t)255;
    return r;
  };
  float* h_var = (float*)alloc((size_t)V_N * H_N * 4);
  float* h_con = (float*)alloc((size_t)C_N * H_N * 4);
  float* t_buf = (float*)alloc((size_t)V_N * H_N * 4);
  int* cnt_c = (int*)alloc((size_t)C_N * 4);
  int* cnt_v = (int*)alloc((size_t)V_N * 4);
  int* rs_c = (int*)alloc((size_t)(C_N + 1) * 4);
  int* rs_v = (int*)alloc((size_t)(V_N + 1) * 4);
  int* head_c = (int*)alloc((size_t)C_N * 4);
  int* head_v = (int*)alloc((size_t)V_N * 4);
  int* next_c = (int*)alloc((size_t)E_N * 4);
  int* next_v = (int*)alloc((size_t)E_N * 4);
  int* src_c = (int*)alloc((size_t)E_N * 4);
  int* src_v = (int*)alloc((size_t)E_N * 4);
  int* part_c = (int*)alloc(64 * 4);
  int* part_v = (int*)alloc(64 * 4);

  hipMemsetAsync(cnt_c, 0, (size_t)C_N * 4, stream);
  hipMemsetAsync(cnt_v, 0, (size_t)V_N * 4, stream);
  hipMemsetAsync(head_c, 0xFF, (size_t)C_N * 4, stream);
  hipMemsetAsync(head_v, 0xFF, (size_t)V_N * 4, stream);

  hist_k<<<(E_N + 255) / 256, 256, 0, stream>>>(var_idx, constr_idx, cnt_c, cnt_v);

  int nb_c = (C_N + SCAN_CHUNK - 1) / SCAN_CHUNK;
  int nb_v = (V_N + SCAN_CHUNK - 1) / SCAN_CHUNK;
  scan_partial<<<nb_c, 256, 0, stream>>>(cnt_c, C_N, part_c);
  scan_partial<<<nb_v, 256, 0, stream>>>(cnt_v, V_N, part_v);
  scan_final<<<nb_c, 256, 0, stream>>>(cnt_c, C_N, part_c, nb_c, rs_c);
  scan_final<<<nb_v, 256, 0, stream>>>(cnt_v, V_N, part_v, nb_v, rs_v);

  build_list<<<(E_N + 255) / 256, 256, 0, stream>>>(var_idx, constr_idx,
                                                    head_c, head_v, next_c, next_v);
  flatten_k<<<(C_N + 255) / 256, 256, 0, stream>>>(head_c, next_c, var_idx, rs_c, src_c, C_N);
  flatten_k<<<(V_N + 255) / 256, 256, 0, stream>>>(head_v, next_v, constr_idx, rs_v, src_v, V_N);

  init_mlp<<<(V_N + 15) / 16, 256, 0, stream>>>(var_feat, W_var, b_var, h_var, V_N);
  init_mlp<<<(C_N + 15) / 16, 256, 0, stream>>>(con_feat, W_con, b_con, h_con, C_N);

  for (int r = 0; r < ROUNDS; ++r) {
    dense64<<<(V_N + 15) / 16, 256, 0, stream>>>(h_var, W_v2c, t_buf, V_N);
    gather_update<<<(C_N + 15) / 16, 256, 0, stream>>>(t_buf, rs_c, src_c, b_v2c, h_con, C_N);
    dense64<<<(C_N + 15) / 16, 256, 0, stream>>>(h_con, W_c2v, t_buf, C_N);
    gather_update<<<(V_N + 15) / 16, 256, 0, stream>>>(t_buf, rs_v, src_v, b_c2v, h_var, V_N);
  }

  score_k<<<(V_N + 15) / 16, 256, 0, stream>>>(h_var, W_score, b_score, out, V_N);
}

// Round 3
// 663.938 us; speedup vs baseline: 1.2525x; 1.1895x over previous
//
#include <hip/hip_runtime.h>

#define V_N 100000
#define C_N 50000
#define E_N 1250000
#define VF_N 32
#define H_N 64
#define ROUNDS 3
#define SCAN_CHUNK 4096

// ---------------- CSR build: linked-list + chain-count + scan + flatten ----------------
// No histogram atomics: counts are derived by walking the chains (L2/L3-resident
// reads) instead of 2.5M device-scope atomicAdds (32B write-through each).

__global__ __launch_bounds__(256) void build_list(const int* __restrict__ vi,
                                                  const int* __restrict__ ci,
                                                  int* __restrict__ head_c,
                                                  int* __restrict__ head_v,
                                                  int* __restrict__ next_c,
                                                  int* __restrict__ next_v) {
  int i = blockIdx.x * 256 + threadIdx.x;
  if (i >= E_N) return;
  next_c[i] = atomicExch(&head_c[ci[i]], i);
  next_v[i] = atomicExch(&head_v[vi[i]], i);
}

__global__ __launch_bounds__(256) void count_both(const int* __restrict__ head_c,
                                                  const int* __restrict__ next_c,
                                                  const int* __restrict__ head_v,
                                                  const int* __restrict__ next_v,
                                                  int* __restrict__ cnt_c,
                                                  int* __restrict__ cnt_v) {
  int d = blockIdx.x * 256 + threadIdx.x;
  if (d < C_N) {
    int n = 0;
    for (int e = head_c[d]; e >= 0; e = next_c[e]) ++n;
    cnt_c[d] = n;
  } else if (d < C_N + V_N) {
    int dv = d - C_N;
    int n = 0;
    for (int e = head_v[dv]; e >= 0; e = next_v[e]) ++n;
    cnt_v[dv] = n;
  }
}

__global__ __launch_bounds__(256) void scan_partial(const int* __restrict__ cnt, int n,
                                                    int* __restrict__ part) {
  __shared__ int lds[256];
  int base = blockIdx.x * SCAN_CHUNK;
  int t = threadIdx.x;
  int sum = 0;
  for (int i = t; i < SCAN_CHUNK; i += 256) {
    int idx = base + i;
    sum += (idx < n) ? cnt[idx] : 0;
  }
  lds[t] = sum;
  __syncthreads();
  for (int off = 128; off > 0; off >>= 1) {
    if (t < off) lds[t] += lds[t + off];
    __syncthreads();
  }
  if (t == 0) part[blockIdx.x] = lds[0];
}

__global__ __launch_bounds__(256) void scan_final(const int* __restrict__ cnt, int n,
                                                  const int* __restrict__ part, int nblocks,
                                                  int* __restrict__ rs) {
  __shared__ int lds[256];
  int b = blockIdx.x, t = threadIdx.x;
  int offset = 0;
  for (int i = 0; i < b; ++i) offset += part[i];
  int base = b * SCAN_CHUNK + t * 16;
  int vals[16];
  int tot = 0;
#pragma unroll
  for (int i = 0; i < 16; ++i) {
    int idx = base + i;
    int v = (idx < n) ? cnt[idx] : 0;
    vals[i] = tot;
    tot += v;
  }
  lds[t] = tot;
  __syncthreads();
  for (int off = 1; off < 256; off <<= 1) {
    int v = (t >= off) ? lds[t - off] : 0;
    __syncthreads();
    lds[t] += v;
    __syncthreads();
  }
  int texcl = lds[t] - tot;
#pragma unroll
  for (int i = 0; i < 16; ++i) {
    int idx = base + i;
    if (idx < n) rs[idx] = offset + texcl + vals[i];
  }
  if (b == 0 && t == 0) {
    int g = 0;
    for (int i = 0; i < nblocks; ++i) g += part[i];
    rs[n] = g;
  }
}

__global__ __launch_bounds__(256) void flatten_both(const int* __restrict__ head_c,
                                                    const int* __restrict__ next_c,
                                                    const int* __restrict__ vi,
                                                    const int* __restrict__ rs_c,
                                                    int* __restrict__ src_c,
                                                    const int* __restrict__ head_v,
                                                    const int* __restrict__ next_v,
                                                    const int* __restrict__ ci,
                                                    const int* __restrict__ rs_v,
                                                    int* __restrict__ src_v) {
  int d = blockIdx.x * 256 + threadIdx.x;
  if (d < C_N) {
    int p = rs_c[d];
    for (int e = head_c[d]; e >= 0; e = next_c[e]) src_c[p++] = vi[e];
  } else if (d < C_N + V_N) {
    int dv = d - C_N;
    int p = rs_v[dv];
    for (int e = head_v[dv]; e >= 0; e = next_v[e]) src_v[p++] = ci[e];
  }
}

// ---------------- input MLP: h = relu(feat[n,32] @ W[32,64] + b) ----------------

__global__ __launch_bounds__(256) void init_mlp(const float* __restrict__ feat,
                                                const float* __restrict__ W,
                                                const float* __restrict__ b,
                                                float* __restrict__ h, int n) {
  __shared__ float Wl[VF_N * H_N];
  for (int i = threadIdx.x; i < VF_N * H_N; i += 256) Wl[i] = W[i];
  __syncthreads();
  int g = (blockIdx.x * 256 + threadIdx.x) >> 4;
  int lane = threadIdx.x & 15;
  if (g >= n) return;
  float2 rv = *(const float2*)&feat[(size_t)g * VF_N + lane * 2];
  float4 acc = *(const float4*)&b[lane * 4];
#pragma unroll
  for (int k = 0; k < VF_N; ++k) {
    float el = (k & 1) ? rv.y : rv.x;
    float v = __shfl(el, k >> 1, 16);
    float4 w = *(const float4*)&Wl[k * H_N + lane * 4];
    acc.x += v * w.x; acc.y += v * w.y; acc.z += v * w.z; acc.w += v * w.w;
  }
  acc.x = fmaxf(acc.x, 0.f); acc.y = fmaxf(acc.y, 0.f);
  acc.z = fmaxf(acc.z, 0.f); acc.w = fmaxf(acc.w, 0.f);
  *(float4*)&h[(size_t)g * H_N + lane * 4] = acc;
}

// ---------------- fused C-side update ----------------
// segsum commutes with @W, so both 64x64 transforms live on the C side (50K rows):
//   s      = segsum_c(h_var)                 (gather raw rows)
//   h_con  = relu(h_con + s @ W_v2c + b_v2c) (matvec 1)
//   t      = h_con @ W_c2v                   (matvec 2, consumed by gather_v)

__global__ __launch_bounds__(256) void fused_c(const float* __restrict__ h_var,
                                               const int* __restrict__ rs,
                                               const int* __restrict__ src,
                                               const float* __restrict__ W1g,
                                               const float* __restrict__ b1g,
                                               const float* __restrict__ W2g,
                                               float* __restrict__ h_con,
                                               float* __restrict__ t_out) {
  __shared__ float W1[H_N * H_N];
  __shared__ float W2[H_N * H_N];
  for (int i = threadIdx.x; i < H_N * H_N; i += 256) { W1[i] = W1g[i]; W2[i] = W2g[i]; }
  __syncthreads();
  int g = (blockIdx.x * 256 + threadIdx.x) >> 4;
  int lane = threadIdx.x & 15;
  if (g >= C_N) return;
  int s = rs[g], e = rs[g + 1];
  float4 acc = {0.f, 0.f, 0.f, 0.f};
  for (int p = s; p < e; p += 16) {
    int cnt = e - p;
    if (cnt > 16) cnt = 16;
    int myidx = (lane < cnt) ? src[p + lane] : 0;
    for (int j = 0; j < cnt; ++j) {
      int sj = __shfl(myidx, j, 16);
      float4 v = *(const float4*)&h_var[(size_t)sj * H_N + lane * 4];
      acc.x += v.x; acc.y += v.y; acc.z += v.z; acc.w += v.w;
    }
  }
  // m = acc @ W1
  float4 m = {0.f, 0.f, 0.f, 0.f};
#pragma unroll
  for (int k = 0; k < H_N; ++k) {
    int sel = k & 3;
    float el = (sel == 0) ? acc.x : (sel == 1) ? acc.y : (sel == 2) ? acc.z : acc.w;
    float v = __shfl(el, k >> 2, 16);
    float4 w = *(const float4*)&W1[k * H_N + lane * 4];
    m.x += v * w.x; m.y += v * w.y; m.z += v * w.z; m.w += v * w.w;
  }
  float4 hv = *(const float4*)&h_con[(size_t)g * H_N + lane * 4];
  float4 b4 = *(const float4*)&b1g[lane * 4];
  float4 hn;
  hn.x = fmaxf(hv.x + m.x + b4.x, 0.f);
  hn.y = fmaxf(hv.y + m.y + b4.y, 0.f);
  hn.z = fmaxf(hv.z + m.z + b4.z, 0.f);
  hn.w = fmaxf(hv.w + m.w + b4.w, 0.f);
  *(float4*)&h_con[(size_t)g * H_N + lane * 4] = hn;
  // t = hn @ W2
  float4 t = {0.f, 0.f, 0.f, 0.f};
#pragma unroll
  for (int k = 0; k < H_N; ++k) {
    int sel = k & 3;
    float el = (sel == 0) ? hn.x : (sel == 1) ? hn.y : (sel == 2) ? hn.z : hn.w;
    float v = __shfl(el, k >> 2, 16);
    float4 w = *(const float4*)&W2[k * H_N + lane * 4];
    t.x += v * w.x; t.y += v * w.y; t.z += v * w.z; t.w += v * w.w;
  }
  *(float4*)&t_out[(size_t)g * H_N + lane * 4] = t;
}

// ---------------- V-side gather (+ optional fused score epilogue) ----------------
// h_var = relu(h_var + segsum_v(t) + b_c2v); last round emits scores instead.

template <int DO_SCORE>
__global__ __launch_bounds__(256) void gather_v_k(const float* __restrict__ t,
                                                  const int* __restrict__ rs,
                                                  const int* __restrict__ src,
                                                  const float* __restrict__ bias,
                                                  float* __restrict__ h,
                                                  const float* __restrict__ Ws,
                                                  const float* __restrict__ bs,
                                                  float* __restrict__ out) {
  int g = (blockIdx.x * 256 + threadIdx.x) >> 4;
  int lane = threadIdx.x & 15;
  if (g >= V_N) return;
  int s = rs[g], e = rs[g + 1];
  float4 acc = {0.f, 0.f, 0.f, 0.f};
  for (int p = s; p < e; p += 16) {
    int cnt = e - p;
    if (cnt > 16) cnt = 16;
    int myidx = (lane < cnt) ? src[p + lane] : 0;
    for (int j = 0; j < cnt; ++j) {
      int sj = __shfl(myidx, j, 16);
      float4 v = *(const float4*)&t[(size_t)sj * H_N + lane * 4];
      acc.x += v.x; acc.y += v.y; acc.z += v.z; acc.w += v.w;
    }
  }
  float4 hv = *(const float4*)&h[(size_t)g * H_N + lane * 4];
  float4 b4 = *(const float4*)&bias[lane * 4];
  float4 hn;
  hn.x = fmaxf(hv.x + acc.x + b4.x, 0.f);
  hn.y = fmaxf(hv.y + acc.y + b4.y, 0.f);
  hn.z = fmaxf(hv.z + acc.z + b4.z, 0.f);
  hn.w = fmaxf(hv.w + acc.w + b4.w, 0.f);
  if (DO_SCORE) {
    float4 w = *(const float4*)&Ws[lane * 4];
    float d = hn.x * w.x + hn.y * w.y + hn.z * w.z + hn.w * w.w;
    d += __shfl_down(d, 8, 16);
    d += __shfl_down(d, 4, 16);
    d += __shfl_down(d, 2, 16);
    d += __shfl_down(d, 1, 16);
    if (lane == 0) out[g] = d + bs[0];
  } else {
    *(float4*)&h[(size_t)g * H_N + lane * 4] = hn;
  }
}

// ---------------- launch ----------------

extern "C" void kernel_launch(void* const* d_in, const int* in_sizes, int n_in,
                              void* d_out, int out_size, void* d_ws, size_t ws_size,
                              hipStream_t stream) {
  const float* var_feat = (const float*)d_in[0];
  const float* con_feat = (const float*)d_in[1];
  const float* W_var = (const float*)d_in[2];
  const float* b_var = (const float*)d_in[3];
  const float* W_con = (const float*)d_in[4];
  const float* b_con = (const float*)d_in[5];
  const float* W_v2c = (const float*)d_in[6];
  const float* b_v2c = (const float*)d_in[7];
  const float* W_c2v = (const float*)d_in[8];
  const float* b_c2v = (const float*)d_in[9];
  const float* W_score = (const float*)d_in[10];
  const float* b_score = (const float*)d_in[11];
  const int* var_idx = (const int*)d_in[12];
  const int* constr_idx = (const int*)d_in[13];
  float* out = (float*)d_out;

  char* p = (char*)d_ws;
  auto alloc = [&](size_t bytes) {
    char* r = p;
    p += (bytes + 255) & ~(size_t)255;
    return r;
  };
  float* h_var = (float*)alloc((size_t)V_N * H_N * 4);
  float* h_con = (float*)alloc((size_t)C_N * H_N * 4);
  float* t_buf = (float*)alloc((size_t)C_N * H_N * 4);
  int* cnt_c = (int*)alloc((size_t)C_N * 4);
  int* cnt_v = (int*)alloc((size_t)V_N * 4);
  int* rs_c = (int*)alloc((size_t)(C_N + 1) * 4);
  int* rs_v = (int*)alloc((size_t)(V_N + 1) * 4);
  int* head_c = (int*)alloc((size_t)C_N * 4);
  int* head_v = (int*)alloc((size_t)V_N * 4);
  int* next_c = (int*)alloc((size_t)E_N * 4);
  int* next_v = (int*)alloc((size_t)E_N * 4);
  int* src_c = (int*)alloc((size_t)E_N * 4);
  int* src_v = (int*)alloc((size_t)E_N * 4);
  int* part_c = (int*)alloc(64 * 4);
  int* part_v = (int*)alloc(64 * 4);

  hipMemsetAsync(head_c, 0xFF, (size_t)C_N * 4, stream);
  hipMemsetAsync(head_v, 0xFF, (size_t)V_N * 4, stream);

  build_list<<<(E_N + 255) / 256, 256, 0, stream>>>(var_idx, constr_idx,
                                                    head_c, head_v, next_c, next_v);
  count_both<<<(C_N + V_N + 255) / 256, 256, 0, stream>>>(head_c, next_c, head_v, next_v,
                                                          cnt_c, cnt_v);

  int nb_c = (C_N + SCAN_CHUNK - 1) / SCAN_CHUNK;
  int nb_v = (V_N + SCAN_CHUNK - 1) / SCAN_CHUNK;
  scan_partial<<<nb_c, 256, 0, stream>>>(cnt_c, C_N, part_c);
  scan_partial<<<nb_v, 256, 0, stream>>>(cnt_v, V_N, part_v);
  scan_final<<<nb_c, 256, 0, stream>>>(cnt_c, C_N, part_c, nb_c, rs_c);
  scan_final<<<nb_v, 256, 0, stream>>>(cnt_v, V_N, part_v, nb_v, rs_v);

  flatten_both<<<(C_N + V_N + 255) / 256, 256, 0, stream>>>(
      head_c, next_c, var_idx, rs_c, src_c,
      head_v, next_v, constr_idx, rs_v, src_v);

  init_mlp<<<(V_N + 15) / 16, 256, 0, stream>>>(var_feat, W_var, b_var, h_var, V_N);
  init_mlp<<<(C_N + 15) / 16, 256, 0, stream>>>(con_feat, W_con, b_con, h_con, C_N);

  for (int r = 0; r < ROUNDS; ++r) {
    fused_c<<<(C_N + 15) / 16, 256, 0, stream>>>(h_var, rs_c, src_c,
                                                 W_v2c, b_v2c, W_c2v, h_con, t_buf);
    if (r < ROUNDS - 1) {
      gather_v_k<0><<<(V_N + 15) / 16, 256, 0, stream>>>(t_buf, rs_v, src_v, b_c2v, h_var,
                                                         nullptr, nullptr, nullptr);
    } else {
      gather_v_k<1><<<(V_N + 15) / 16, 256, 0, stream>>>(t_buf, rs_v, src_v, b_c2v, h_var,
                                                         W_score, b_score, out);
    }
  }
}

// Round 4
// 614.615 us; speedup vs baseline: 1.3530x; 1.0802x over previous
//
#include <hip/hip_runtime.h>

typedef unsigned short u16;
typedef unsigned int u32;

#define V_N 100000
#define C_N 50000
#define E_N 1250000
#define VF_N 32
#define H_N 64
#define ROUNDS 3
#define SCAN_CHUNK 4096

static __device__ __forceinline__ float bf2f(u16 x) {
  return __uint_as_float(((u32)x) << 16);
}
static __device__ __forceinline__ u16 f2bf(float f) {
  u32 u = __float_as_uint(f);
  u32 r = (u + 0x7fff + ((u >> 16) & 1)) >> 16;  // RNE
  return (u16)r;
}

// ---------------- CSR build: linked-list + chain-count + scan + flatten ----------------

__global__ __launch_bounds__(256) void build_list(const int* __restrict__ vi,
                                                  const int* __restrict__ ci,
                                                  int* __restrict__ head_c,
                                                  int* __restrict__ head_v,
                                                  int* __restrict__ next_c,
                                                  int* __restrict__ next_v) {
  int i = blockIdx.x * 256 + threadIdx.x;
  if (i >= E_N) return;
  next_c[i] = atomicExch(&head_c[ci[i]], i);
  next_v[i] = atomicExch(&head_v[vi[i]], i);
}

__global__ __launch_bounds__(256) void count_both(const int* __restrict__ head_c,
                                                  const int* __restrict__ next_c,
                                                  const int* __restrict__ head_v,
                                                  const int* __restrict__ next_v,
                                                  int* __restrict__ cnt_c,
                                                  int* __restrict__ cnt_v) {
  int d = blockIdx.x * 256 + threadIdx.x;
  if (d < C_N) {
    int n = 0;
    for (int e = head_c[d]; e >= 0; e = next_c[e]) ++n;
    cnt_c[d] = n;
  } else if (d < C_N + V_N) {
    int dv = d - C_N;
    int n = 0;
    for (int e = head_v[dv]; e >= 0; e = next_v[e]) ++n;
    cnt_v[dv] = n;
  }
}

__global__ __launch_bounds__(256) void scan_partial(const int* __restrict__ cnt, int n,
                                                    int* __restrict__ part) {
  __shared__ int lds[256];
  int base = blockIdx.x * SCAN_CHUNK;
  int t = threadIdx.x;
  int sum = 0;
  for (int i = t; i < SCAN_CHUNK; i += 256) {
    int idx = base + i;
    sum += (idx < n) ? cnt[idx] : 0;
  }
  lds[t] = sum;
  __syncthreads();
  for (int off = 128; off > 0; off >>= 1) {
    if (t < off) lds[t] += lds[t + off];
    __syncthreads();
  }
  if (t == 0) part[blockIdx.x] = lds[0];
}

__global__ __launch_bounds__(256) void scan_final(const int* __restrict__ cnt, int n,
                                                  const int* __restrict__ part, int nblocks,
                                                  int* __restrict__ rs) {
  __shared__ int lds[256];
  int b = blockIdx.x, t = threadIdx.x;
  int offset = 0;
  for (int i = 0; i < b; ++i) offset += part[i];
  int base = b * SCAN_CHUNK + t * 16;
  int vals[16];
  int tot = 0;
#pragma unroll
  for (int i = 0; i < 16; ++i) {
    int idx = base + i;
    int v = (idx < n) ? cnt[idx] : 0;
    vals[i] = tot;
    tot += v;
  }
  lds[t] = tot;
  __syncthreads();
  for (int off = 1; off < 256; off <<= 1) {
    int v = (t >= off) ? lds[t - off] : 0;
    __syncthreads();
    lds[t] += v;
    __syncthreads();
  }
  int texcl = lds[t] - tot;
#pragma unroll
  for (int i = 0; i < 16; ++i) {
    int idx = base + i;
    if (idx < n) rs[idx] = offset + texcl + vals[i];
  }
  if (b == 0 && t == 0) {
    int g = 0;
    for (int i = 0; i < nblocks; ++i) g += part[i];
    rs[n] = g;
  }
}

__global__ __launch_bounds__(256) void flatten_both(const int* __restrict__ head_c,
                                                    const int* __restrict__ next_c,
                                                    const int* __restrict__ vi,
                                                    const int* __restrict__ rs_c,
                                                    int* __restrict__ src_c,
                                                    const int* __restrict__ head_v,
                                                    const int* __restrict__ next_v,
                                                    const int* __restrict__ ci,
                                                    const int* __restrict__ rs_v,
                                                    int* __restrict__ src_v) {
  int d = blockIdx.x * 256 + threadIdx.x;
  if (d < C_N) {
    int p = rs_c[d];
    for (int e = head_c[d]; e >= 0; e = next_c[e]) src_c[p++] = vi[e];
  } else if (d < C_N + V_N) {
    int dv = d - C_N;
    int p = rs_v[dv];
    for (int e = head_v[dv]; e >= 0; e = next_v[e]) src_v[p++] = ci[e];
  }
}

// ---------------- input MLP: h = relu(feat[n,32] @ W[32,64] + b) ----------------
// WRITE_BF: also emit bf16 mirror (gather payload for the C-side pass).

template <int WRITE_BF>
__global__ __launch_bounds__(256) void init_mlp(const float* __restrict__ feat,
                                                const float* __restrict__ W,
                                                const float* __restrict__ b,
                                                float* __restrict__ h,
                                                u16* __restrict__ hbf, int n) {
  __shared__ float Wl[VF_N * H_N];
  for (int i = threadIdx.x; i < VF_N * H_N; i += 256) Wl[i] = W[i];
  __syncthreads();
  int g = (blockIdx.x * 256 + threadIdx.x) >> 4;
  int lane = threadIdx.x & 15;
  if (g >= n) return;
  float2 rv = *(const float2*)&feat[(size_t)g * VF_N + lane * 2];
  float4 acc = *(const float4*)&b[lane * 4];
#pragma unroll
  for (int k = 0; k < VF_N; ++k) {
    float el = (k & 1) ? rv.y : rv.x;
    float v = __shfl(el, k >> 1, 16);
    float4 w = *(const float4*)&Wl[k * H_N + lane * 4];
    acc.x += v * w.x; acc.y += v * w.y; acc.z += v * w.z; acc.w += v * w.w;
  }
  acc.x = fmaxf(acc.x, 0.f); acc.y = fmaxf(acc.y, 0.f);
  acc.z = fmaxf(acc.z, 0.f); acc.w = fmaxf(acc.w, 0.f);
  *(float4*)&h[(size_t)g * H_N + lane * 4] = acc;
  if (WRITE_BF) {
    ushort4 q;
    q.x = f2bf(acc.x); q.y = f2bf(acc.y); q.z = f2bf(acc.z); q.w = f2bf(acc.w);
    *(ushort4*)&hbf[(size_t)g * H_N + lane * 4] = q;
  }
}

// ---------------- fused C-side update ----------------
//   s      = segsum_c(h_var_bf)              (bf16 gather, fp32 accumulate)
//   h_con  = relu(h_con + s @ W_v2c + b_v2c)
//   t_bf   = bf16(h_con @ W_c2v)             (payload for the V-side gather)

__global__ __launch_bounds__(256) void fused_c(const u16* __restrict__ h_var_bf,
                                               const int* __restrict__ rs,
                                               const int* __restrict__ src,
                                               const float* __restrict__ W1g,
                                               const float* __restrict__ b1g,
                                               const float* __restrict__ W2g,
                                               float* __restrict__ h_con,
                                               u16* __restrict__ t_out) {
  __shared__ float W1[H_N * H_N];
  __shared__ float W2[H_N * H_N];
  for (int i = threadIdx.x; i < H_N * H_N; i += 256) { W1[i] = W1g[i]; W2[i] = W2g[i]; }
  __syncthreads();
  int g = (blockIdx.x * 256 + threadIdx.x) >> 4;
  int lane = threadIdx.x & 15;
  if (g >= C_N) return;
  int s = rs[g], e = rs[g + 1];
  float4 acc = {0.f, 0.f, 0.f, 0.f};
  for (int p = s; p < e; p += 16) {
    int cnt = e - p;
    if (cnt > 16) cnt = 16;
    int myidx = (lane < cnt) ? src[p + lane] : 0;
    for (int j = 0; j < cnt; ++j) {
      int sj = __shfl(myidx, j, 16);
      ushort4 v = *(const ushort4*)&h_var_bf[(size_t)sj * H_N + lane * 4];
      acc.x += bf2f(v.x); acc.y += bf2f(v.y); acc.z += bf2f(v.z); acc.w += bf2f(v.w);
    }
  }
  // m = acc @ W1
  float4 m = {0.f, 0.f, 0.f, 0.f};
#pragma unroll
  for (int k = 0; k < H_N; ++k) {
    int sel = k & 3;
    float el = (sel == 0) ? acc.x : (sel == 1) ? acc.y : (sel == 2) ? acc.z : acc.w;
    float v = __shfl(el, k >> 2, 16);
    float4 w = *(const float4*)&W1[k * H_N + lane * 4];
    m.x += v * w.x; m.y += v * w.y; m.z += v * w.z; m.w += v * w.w;
  }
  float4 hv = *(const float4*)&h_con[(size_t)g * H_N + lane * 4];
  float4 b4 = *(const float4*)&b1g[lane * 4];
  float4 hn;
  hn.x = fmaxf(hv.x + m.x + b4.x, 0.f);
  hn.y = fmaxf(hv.y + m.y + b4.y, 0.f);
  hn.z = fmaxf(hv.z + m.z + b4.z, 0.f);
  hn.w = fmaxf(hv.w + m.w + b4.w, 0.f);
  *(float4*)&h_con[(size_t)g * H_N + lane * 4] = hn;
  // t = hn @ W2 -> bf16
  float4 t = {0.f, 0.f, 0.f, 0.f};
#pragma unroll
  for (int k = 0; k < H_N; ++k) {
    int sel = k & 3;
    float el = (sel == 0) ? hn.x : (sel == 1) ? hn.y : (sel == 2) ? hn.z : hn.w;
    float v = __shfl(el, k >> 2, 16);
    float4 w = *(const float4*)&W2[k * H_N + lane * 4];
    t.x += v * w.x; t.y += v * w.y; t.z += v * w.z; t.w += v * w.w;
  }
  ushort4 q;
  q.x = f2bf(t.x); q.y = f2bf(t.y); q.z = f2bf(t.z); q.w = f2bf(t.w);
  *(ushort4*)&t_out[(size_t)g * H_N + lane * 4] = q;
}

// ---------------- V-side gather (+ fused score epilogue on last round) ----------------
// h_var = relu(h_var + segsum_v(t_bf) + b_c2v); last round emits scores only.

template <int DO_SCORE>
__global__ __launch_bounds__(256) void gather_v_k(const u16* __restrict__ t,
                                                  const int* __restrict__ rs,
                                                  const int* __restrict__ src,
                                                  const float* __restrict__ bias,
                                                  float* __restrict__ h,
                                                  u16* __restrict__ hbf,
                                                  const float* __restrict__ Ws,
                                                  const float* __restrict__ bs,
                                                  float* __restrict__ out) {
  int g = (blockIdx.x * 256 + threadIdx.x) >> 4;
  int lane = threadIdx.x & 15;
  if (g >= V_N) return;
  int s = rs[g], e = rs[g + 1];
  float4 acc = {0.f, 0.f, 0.f, 0.f};
  for (int p = s; p < e; p += 16) {
    int cnt = e - p;
    if (cnt > 16) cnt = 16;
    int myidx = (lane < cnt) ? src[p + lane] : 0;
    for (int j = 0; j < cnt; ++j) {
      int sj = __shfl(myidx, j, 16);
      ushort4 v = *(const ushort4*)&t[(size_t)sj * H_N + lane * 4];
      acc.x += bf2f(v.x); acc.y += bf2f(v.y); acc.z += bf2f(v.z); acc.w += bf2f(v.w);
    }
  }
  float4 hv = *(const float4*)&h[(size_t)g * H_N + lane * 4];
  float4 b4 = *(const float4*)&bias[lane * 4];
  float4 hn;
  hn.x = fmaxf(hv.x + acc.x + b4.x, 0.f);
  hn.y = fmaxf(hv.y + acc.y + b4.y, 0.f);
  hn.z = fmaxf(hv.z + acc.z + b4.z, 0.f);
  hn.w = fmaxf(hv.w + acc.w + b4.w, 0.f);
  if (DO_SCORE) {
    float4 w = *(const float4*)&Ws[lane * 4];
    float d = hn.x * w.x + hn.y * w.y + hn.z * w.z + hn.w * w.w;
    d += __shfl_down(d, 8, 16);
    d += __shfl_down(d, 4, 16);
    d += __shfl_down(d, 2, 16);
    d += __shfl_down(d, 1, 16);
    if (lane == 0) out[g] = d + bs[0];
  } else {
    *(float4*)&h[(size_t)g * H_N + lane * 4] = hn;
    ushort4 q;
    q.x = f2bf(hn.x); q.y = f2bf(hn.y); q.z = f2bf(hn.z); q.w = f2bf(hn.w);
    *(ushort4*)&hbf[(size_t)g * H_N + lane * 4] = q;
  }
}

// ---------------- launch ----------------

extern "C" void kernel_launch(void* const* d_in, const int* in_sizes, int n_in,
                              void* d_out, int out_size, void* d_ws, size_t ws_size,
                              hipStream_t stream) {
  const float* var_feat = (const float*)d_in[0];
  const float* con_feat = (const float*)d_in[1];
  const float* W_var = (const float*)d_in[2];
  const float* b_var = (const float*)d_in[3];
  const float* W_con = (const float*)d_in[4];
  const float* b_con = (const float*)d_in[5];
  const float* W_v2c = (const float*)d_in[6];
  const float* b_v2c = (const float*)d_in[7];
  const float* W_c2v = (const float*)d_in[8];
  const float* b_c2v = (const float*)d_in[9];
  const float* W_score = (const float*)d_in[10];
  const float* b_score = (const float*)d_in[11];
  const int* var_idx = (const int*)d_in[12];
  const int* constr_idx = (const int*)d_in[13];
  float* out = (float*)d_out;

  char* p = (char*)d_ws;
  auto alloc = [&](size_t bytes) {
    char* r = p;
    p += (bytes + 255) & ~(size_t)255;
    return r;
  };
  float* h_var = (float*)alloc((size_t)V_N * H_N * 4);
  u16* h_var_bf = (u16*)alloc((size_t)V_N * H_N * 2);
  float* h_con = (float*)alloc((size_t)C_N * H_N * 4);
  u16* t_bf = (u16*)alloc((size_t)C_N * H_N * 2);
  int* cnt_c = (int*)alloc((size_t)C_N * 4);
  int* cnt_v = (int*)alloc((size_t)V_N * 4);
  int* rs_c = (int*)alloc((size_t)(C_N + 1) * 4);
  int* rs_v = (int*)alloc((size_t)(V_N + 1) * 4);
  int* head_c = (int*)alloc((size_t)C_N * 4);
  int* head_v = (int*)alloc((size_t)V_N * 4);
  int* next_c = (int*)alloc((size_t)E_N * 4);
  int* next_v = (int*)alloc((size_t)E_N * 4);
  int* src_c = (int*)alloc((size_t)E_N * 4);
  int* src_v = (int*)alloc((size_t)E_N * 4);
  int* part_c = (int*)alloc(64 * 4);
  int* part_v = (int*)alloc(64 * 4);

  hipMemsetAsync(head_c, 0xFF, (size_t)C_N * 4, stream);
  hipMemsetAsync(head_v, 0xFF, (size_t)V_N * 4, stream);

  build_list<<<(E_N + 255) / 256, 256, 0, stream>>>(var_idx, constr_idx,
                                                    head_c, head_v, next_c, next_v);
  count_both<<<(C_N + V_N + 255) / 256, 256, 0, stream>>>(head_c, next_c, head_v, next_v,
                                                          cnt_c, cnt_v);

  int nb_c = (C_N + SCAN_CHUNK - 1) / SCAN_CHUNK;
  int nb_v = (V_N + SCAN_CHUNK - 1) / SCAN_CHUNK;
  scan_partial<<<nb_c, 256, 0, stream>>>(cnt_c, C_N, part_c);
  scan_partial<<<nb_v, 256, 0, stream>>>(cnt_v, V_N, part_v);
  scan_final<<<nb_c, 256, 0, stream>>>(cnt_c, C_N, part_c, nb_c, rs_c);
  scan_final<<<nb_v, 256, 0, stream>>>(cnt_v, V_N, part_v, nb_v, rs_v);

  flatten_both<<<(C_N + V_N + 255) / 256, 256, 0, stream>>>(
      head_c, next_c, var_idx, rs_c, src_c,
      head_v, next_v, constr_idx, rs_v, src_v);

  init_mlp<1><<<(V_N + 15) / 16, 256, 0, stream>>>(var_feat, W_var, b_var, h_var, h_var_bf, V_N);
  init_mlp<0><<<(C_N + 15) / 16, 256, 0, stream>>>(con_feat, W_con, b_con, h_con, nullptr, C_N);

  for (int r = 0; r < ROUNDS; ++r) {
    fused_c<<<(C_N + 15) / 16, 256, 0, stream>>>(h_var_bf, rs_c, src_c,
                                                 W_v2c, b_v2c, W_c2v, h_con, t_bf);
    if (r < ROUNDS - 1) {
      gather_v_k<0><<<(V_N + 15) / 16, 256, 0, stream>>>(t_bf, rs_v, src_v, b_c2v, h_var,
                                                         h_var_bf, nullptr, nullptr, nullptr);
    } else {
      gather_v_k<1><<<(V_N + 15) / 16, 256, 0, stream>>>(t_bf, rs_v, src_v, b_c2v, h_var,
                                                         nullptr, W_score, b_score, out);
    }
  }
}

// Round 5
// 449.847 us; speedup vs baseline: 1.8486x; 1.3663x over previous
//
#include <hip/hip_runtime.h>

typedef unsigned short u16;
typedef unsigned int u32;

#define V_N 100000
#define C_N 50000
#define E_N 1250000
#define VF_N 32
#define H_N 64
#define ROUNDS 3

#define TILE 4096
#define NT ((E_N + TILE - 1) / TILE)      // 306 edge tiles
#define NB_C ((C_N + 127) / 128)          // 391 coarse buckets (128 dests each)
#define NB_V ((V_N + 255) / 256)          // 391 coarse buckets (256 dests each)

static __device__ __forceinline__ float bf2f(u16 x) {
  return __uint_as_float(((u32)x) << 16);
}
static __device__ __forceinline__ u16 f2bf(float f) {
  u32 u = __float_as_uint(f);
  u32 r = (u + 0x7fff + ((u >> 16) & 1)) >> 16;  // RNE
  return (u16)r;
}

// ---------------- CSR build: two-level bucket sort, block-aggregated atomics ----

__global__ __launch_bounds__(256) void bucket_hist(const int* __restrict__ vi,
                                                   const int* __restrict__ ci,
                                                   int* __restrict__ gh_c,
                                                   int* __restrict__ gh_v) {
  __shared__ int hc[NB_C], hv[NB_V];
  int t = threadIdx.x;
  for (int j = t; j < NB_C; j += 256) hc[j] = 0;
  for (int j = t; j < NB_V; j += 256) hv[j] = 0;
  __syncthreads();
  int base = blockIdx.x * TILE;
#pragma unroll
  for (int i = 0; i < 16; ++i) {
    int idx = base + i * 256 + t;
    if (idx < E_N) {
      atomicAdd(&hc[ci[idx] >> 7], 1);
      atomicAdd(&hv[vi[idx] >> 8], 1);
    }
  }
  __syncthreads();
  for (int j = t; j < NB_C; j += 256) if (hc[j]) atomicAdd(&gh_c[j], hc[j]);
  for (int j = t; j < NB_V; j += 256) if (hv[j]) atomicAdd(&gh_v[j], hv[j]);
}

__global__ __launch_bounds__(512) void bucket_scan(const int* __restrict__ gh_c,
                                                   const int* __restrict__ gh_v,
                                                   int* __restrict__ base_c,
                                                   int* __restrict__ cursor_c,
                                                   int* __restrict__ base_v,
                                                   int* __restrict__ cursor_v,
                                                   int* __restrict__ rs_c,
                                                   int* __restrict__ rs_v) {
  __shared__ int lds[512];
  int t = threadIdx.x;
  // c side
  int x = (t < NB_C) ? gh_c[t] : 0;
  lds[t] = x;
  __syncthreads();
  for (int off = 1; off < 512; off <<= 1) {
    int v = (t >= off) ? lds[t - off] : 0;
    __syncthreads();
    lds[t] += v;
    __syncthreads();
  }
  int excl = lds[t] - x;
  if (t < NB_C) { base_c[t] = excl; cursor_c[t] = excl; }
  if (t == 511) base_c[NB_C] = lds[511];
  __syncthreads();
  // v side
  int y = (t < NB_V) ? gh_v[t] : 0;
  lds[t] = y;
  __syncthreads();
  for (int off = 1; off < 512; off <<= 1) {
    int v = (t >= off) ? lds[t - off] : 0;
    __syncthreads();
    lds[t] += v;
    __syncthreads();
  }
  int excl2 = lds[t] - y;
  if (t < NB_V) { base_v[t] = excl2; cursor_v[t] = excl2; }
  if (t == 511) base_v[NB_V] = lds[511];
  if (t == 0) { rs_c[C_N] = E_N; rs_v[V_N] = E_N; }
}

// Packed element: (local_dest << 17) | src_id   (src < 2^17, local_dest <= 255)
__global__ __launch_bounds__(256) void scatter_pack(const int* __restrict__ vi,
                                                    const int* __restrict__ ci,
                                                    int* __restrict__ cursor_c,
                                                    int* __restrict__ cursor_v,
                                                    int* __restrict__ packed_c,
                                                    int* __restrict__ packed_v) {
  __shared__ int hc[NB_C], hv[NB_V], sc[NB_C], sv[NB_V];
  int t = threadIdx.x;
  for (int j = t; j < NB_C; j += 256) hc[j] = 0;
  for (int j = t; j < NB_V; j += 256) hv[j] = 0;
  __syncthreads();
  int base = blockIdx.x * TILE;
  int cc[16], vv[16];
#pragma unroll
  for (int i = 0; i < 16; ++i) {
    int idx = base + i * 256 + t;
    if (idx < E_N) {
      cc[i] = ci[idx];
      vv[i] = vi[idx];
      atomicAdd(&hc[cc[i] >> 7], 1);
      atomicAdd(&hv[vv[i] >> 8], 1);
    } else {
      cc[i] = -1;
      vv[i] = -1;
    }
  }
  __syncthreads();
  // reserve contiguous slices per bucket for this block; reset counters for ranking
  for (int j = t; j < NB_C; j += 256) {
    int n = hc[j];
    if (n > 0) sc[j] = atomicAdd(&cursor_c[j], n);
    hc[j] = 0;
  }
  for (int j = t; j < NB_V; j += 256) {
    int n = hv[j];
    if (n > 0) sv[j] = atomicAdd(&cursor_v[j], n);
    hv[j] = 0;
  }
  __syncthreads();
#pragma unroll
  for (int i = 0; i < 16; ++i) {
    if (cc[i] >= 0) {
      int b = cc[i] >> 7;
      int r = atomicAdd(&hc[b], 1);
      packed_c[sc[b] + r] = ((cc[i] & 127) << 17) | vv[i];
      int b2 = vv[i] >> 8;
      int r2 = atomicAdd(&hv[b2], 1);
      packed_v[sv[b2] + r2] = ((vv[i] & 255) << 17) | cc[i];
    }
  }
}

// Per-bucket counting sort over LOCAL_N local destinations; emits rs and grouped src.
template <int LOCAL_N, int N_DEST>
__global__ __launch_bounds__(256) void fine_sort(const int* __restrict__ packed,
                                                 const int* __restrict__ base,
                                                 int* __restrict__ rs,
                                                 int* __restrict__ srco) {
  __shared__ int cnt[LOCAL_N];
  __shared__ int excl[LOCAL_N];
  int b = blockIdx.x, t = threadIdx.x;
  int s0 = base[b], s1 = base[b + 1];
  if (t < LOCAL_N) cnt[t] = 0;
  __syncthreads();
  for (int i = s0 + t; i < s1; i += 256) atomicAdd(&cnt[packed[i] >> 17], 1);
  __syncthreads();
  if (t == 0) {
    int run = 0;
    for (int k = 0; k < LOCAL_N; ++k) { excl[k] = run; run += cnt[k]; }
  }
  __syncthreads();
  if (t < LOCAL_N) {
    int d = b * LOCAL_N + t;
    if (d < N_DEST) rs[d] = s0 + excl[t];
    cnt[t] = excl[t];  // reuse as running cursor
  }
  __syncthreads();
  for (int i = s0 + t; i < s1; i += 256) {
    int w = packed[i];
    int ld = w >> 17;
    int pos = s0 + atomicAdd(&cnt[ld], 1);
    srco[pos] = w & 0x1FFFF;
  }
}

// ---------------- input MLP: h = relu(feat[n,32] @ W[32,64] + b) ----------------

template <int WRITE_BF>
__global__ __launch_bounds__(256) void init_mlp(const float* __restrict__ feat,
                                                const float* __restrict__ W,
                                                const float* __restrict__ b,
                                                float* __restrict__ h,
                                                u16* __restrict__ hbf, int n) {
  __shared__ float Wl[VF_N * H_N];
  for (int i = threadIdx.x; i < VF_N * H_N; i += 256) Wl[i] = W[i];
  __syncthreads();
  int g = (blockIdx.x * 256 + threadIdx.x) >> 4;
  int lane = threadIdx.x & 15;
  if (g >= n) return;
  float2 rv = *(const float2*)&feat[(size_t)g * VF_N + lane * 2];
  float4 acc = *(const float4*)&b[lane * 4];
#pragma unroll
  for (int k = 0; k < VF_N; ++k) {
    float el = (k & 1) ? rv.y : rv.x;
    float v = __shfl(el, k >> 1, 16);
    float4 w = *(const float4*)&Wl[k * H_N + lane * 4];
    acc.x += v * w.x; acc.y += v * w.y; acc.z += v * w.z; acc.w += v * w.w;
  }
  acc.x = fmaxf(acc.x, 0.f); acc.y = fmaxf(acc.y, 0.f);
  acc.z = fmaxf(acc.z, 0.f); acc.w = fmaxf(acc.w, 0.f);
  *(float4*)&h[(size_t)g * H_N + lane * 4] = acc;
  if (WRITE_BF) {
    ushort4 q;
    q.x = f2bf(acc.x); q.y = f2bf(acc.y); q.z = f2bf(acc.z); q.w = f2bf(acc.w);
    *(ushort4*)&hbf[(size_t)g * H_N + lane * 4] = q;
  }
}

// ---------------- fused C-side update ----------------

__global__ __launch_bounds__(256) void fused_c(const u16* __restrict__ h_var_bf,
                                               const int* __restrict__ rs,
                                               const int* __restrict__ src,
                                               const float* __restrict__ W1g,
                                               const float* __restrict__ b1g,
                                               const float* __restrict__ W2g,
                                               float* __restrict__ h_con,
                                               u16* __restrict__ t_out) {
  __shared__ float W1[H_N * H_N];
  __shared__ float W2[H_N * H_N];
  for (int i = threadIdx.x; i < H_N * H_N; i += 256) { W1[i] = W1g[i]; W2[i] = W2g[i]; }
  __syncthreads();
  int g = (blockIdx.x * 256 + threadIdx.x) >> 4;
  int lane = threadIdx.x & 15;
  if (g >= C_N) return;
  int s = rs[g], e = rs[g + 1];
  float4 acc = {0.f, 0.f, 0.f, 0.f};
  for (int p = s; p < e; p += 16) {
    int cnt = e - p;
    if (cnt > 16) cnt = 16;
    int myidx = (lane < cnt) ? src[p + lane] : 0;
    for (int j = 0; j < cnt; ++j) {
      int sj = __shfl(myidx, j, 16);
      ushort4 v = *(const ushort4*)&h_var_bf[(size_t)sj * H_N + lane * 4];
      acc.x += bf2f(v.x); acc.y += bf2f(v.y); acc.z += bf2f(v.z); acc.w += bf2f(v.w);
    }
  }
  float4 m = {0.f, 0.f, 0.f, 0.f};
#pragma unroll
  for (int k = 0; k < H_N; ++k) {
    int sel = k & 3;
    float el = (sel == 0) ? acc.x : (sel == 1) ? acc.y : (sel == 2) ? acc.z : acc.w;
    float v = __shfl(el, k >> 2, 16);
    float4 w = *(const float4*)&W1[k * H_N + lane * 4];
    m.x += v * w.x; m.y += v * w.y; m.z += v * w.z; m.w += v * w.w;
  }
  float4 hv = *(const float4*)&h_con[(size_t)g * H_N + lane * 4];
  float4 b4 = *(const float4*)&b1g[lane * 4];
  float4 hn;
  hn.x = fmaxf(hv.x + m.x + b4.x, 0.f);
  hn.y = fmaxf(hv.y + m.y + b4.y, 0.f);
  hn.z = fmaxf(hv.z + m.z + b4.z, 0.f);
  hn.w = fmaxf(hv.w + m.w + b4.w, 0.f);
  *(float4*)&h_con[(size_t)g * H_N + lane * 4] = hn;
  float4 tt = {0.f, 0.f, 0.f, 0.f};
#pragma unroll
  for (int k = 0; k < H_N; ++k) {
    int sel = k & 3;
    float el = (sel == 0) ? hn.x : (sel == 1) ? hn.y : (sel == 2) ? hn.z : hn.w;
    float v = __shfl(el, k >> 2, 16);
    float4 w = *(const float4*)&W2[k * H_N + lane * 4];
    tt.x += v * w.x; tt.y += v * w.y; tt.z += v * w.z; tt.w += v * w.w;
  }
  ushort4 q;
  q.x = f2bf(tt.x); q.y = f2bf(tt.y); q.z = f2bf(tt.z); q.w = f2bf(tt.w);
  *(ushort4*)&t_out[(size_t)g * H_N + lane * 4] = q;
}

// ---------------- V-side gather (+ fused score epilogue on last round) ----------

template <int DO_SCORE>
__global__ __launch_bounds__(256) void gather_v_k(const u16* __restrict__ t,
                                                  const int* __restrict__ rs,
                                                  const int* __restrict__ src,
                                                  const float* __restrict__ bias,
                                                  float* __restrict__ h,
                                                  u16* __restrict__ hbf,
                                                  const float* __restrict__ Ws,
                                                  const float* __restrict__ bs,
                                                  float* __restrict__ out) {
  int g = (blockIdx.x * 256 + threadIdx.x) >> 4;
  int lane = threadIdx.x & 15;
  if (g >= V_N) return;
  int s = rs[g], e = rs[g + 1];
  float4 acc = {0.f, 0.f, 0.f, 0.f};
  for (int p = s; p < e; p += 16) {
    int cnt = e - p;
    if (cnt > 16) cnt = 16;
    int myidx = (lane < cnt) ? src[p + lane] : 0;
    for (int j = 0; j < cnt; ++j) {
      int sj = __shfl(myidx, j, 16);
      ushort4 v = *(const ushort4*)&t[(size_t)sj * H_N + lane * 4];
      acc.x += bf2f(v.x); acc.y += bf2f(v.y); acc.z += bf2f(v.z); acc.w += bf2f(v.w);
    }
  }
  float4 hv = *(const float4*)&h[(size_t)g * H_N + lane * 4];
  float4 b4 = *(const float4*)&bias[lane * 4];
  float4 hn;
  hn.x = fmaxf(hv.x + acc.x + b4.x, 0.f);
  hn.y = fmaxf(hv.y + acc.y + b4.y, 0.f);
  hn.z = fmaxf(hv.z + acc.z + b4.z, 0.f);
  hn.w = fmaxf(hv.w + acc.w + b4.w, 0.f);
  if (DO_SCORE) {
    float4 w = *(const float4*)&Ws[lane * 4];
    float d = hn.x * w.x + hn.y * w.y + hn.z * w.z + hn.w * w.w;
    d += __shfl_down(d, 8, 16);
    d += __shfl_down(d, 4, 16);
    d += __shfl_down(d, 2, 16);
    d += __shfl_down(d, 1, 16);
    if (lane == 0) out[g] = d + bs[0];
  } else {
    *(float4*)&h[(size_t)g * H_N + lane * 4] = hn;
    ushort4 q;
    q.x = f2bf(hn.x); q.y = f2bf(hn.y); q.z = f2bf(hn.z); q.w = f2bf(hn.w);
    *(ushort4*)&hbf[(size_t)g * H_N + lane * 4] = q;
  }
}

// ---------------- launch ----------------

extern "C" void kernel_launch(void* const* d_in, const int* in_sizes, int n_in,
                              void* d_out, int out_size, void* d_ws, size_t ws_size,
                              hipStream_t stream) {
  const float* var_feat = (const float*)d_in[0];
  const float* con_feat = (const float*)d_in[1];
  const float* W_var = (const float*)d_in[2];
  const float* b_var = (const float*)d_in[3];
  const float* W_con = (const float*)d_in[4];
  const float* b_con = (const float*)d_in[5];
  const float* W_v2c = (const float*)d_in[6];
  const float* b_v2c = (const float*)d_in[7];
  const float* W_c2v = (const float*)d_in[8];
  const float* b_c2v = (const float*)d_in[9];
  const float* W_score = (const float*)d_in[10];
  const float* b_score = (const float*)d_in[11];
  const int* var_idx = (const int*)d_in[12];
  const int* constr_idx = (const int*)d_in[13];
  float* out = (float*)d_out;

  char* p = (char*)d_ws;
  auto alloc = [&](size_t bytes) {
    char* r = p;
    p += (bytes + 255) & ~(size_t)255;
    return r;
  };
  float* h_var = (float*)alloc((size_t)V_N * H_N * 4);
  u16* h_var_bf = (u16*)alloc((size_t)V_N * H_N * 2);
  float* h_con = (float*)alloc((size_t)C_N * H_N * 4);
  u16* t_bf = (u16*)alloc((size_t)C_N * H_N * 2);
  int* rs_c = (int*)alloc((size_t)(C_N + 1) * 4);
  int* rs_v = (int*)alloc((size_t)(V_N + 1) * 4);
  int* src_c = (int*)alloc((size_t)E_N * 4);
  int* src_v = (int*)alloc((size_t)E_N * 4);
  int* packed_c = (int*)alloc((size_t)E_N * 4);
  int* packed_v = (int*)alloc((size_t)E_N * 4);
  int* ghist_c = (int*)alloc((size_t)NB_C * 4);
  int* ghist_v = (int*)alloc((size_t)NB_V * 4);
  int* base_c = (int*)alloc((size_t)(NB_C + 1) * 4);
  int* base_v = (int*)alloc((size_t)(NB_V + 1) * 4);
  int* cursor_c = (int*)alloc((size_t)NB_C * 4);
  int* cursor_v = (int*)alloc((size_t)NB_V * 4);

  hipMemsetAsync(ghist_c, 0, (size_t)NB_C * 4, stream);
  hipMemsetAsync(ghist_v, 0, (size_t)NB_V * 4, stream);

  bucket_hist<<<NT, 256, 0, stream>>>(var_idx, constr_idx, ghist_c, ghist_v);
  bucket_scan<<<1, 512, 0, stream>>>(ghist_c, ghist_v, base_c, cursor_c,
                                     base_v, cursor_v, rs_c, rs_v);
  scatter_pack<<<NT, 256, 0, stream>>>(var_idx, constr_idx, cursor_c, cursor_v,
                                       packed_c, packed_v);
  fine_sort<128, C_N><<<NB_C, 256, 0, stream>>>(packed_c, base_c, rs_c, src_c);
  fine_sort<256, V_N><<<NB_V, 256, 0, stream>>>(packed_v, base_v, rs_v, src_v);

  init_mlp<1><<<(V_N + 15) / 16, 256, 0, stream>>>(var_feat, W_var, b_var, h_var, h_var_bf, V_N);
  init_mlp<0><<<(C_N + 15) / 16, 256, 0, stream>>>(con_feat, W_con, b_con, h_con, nullptr, C_N);

  for (int r = 0; r < ROUNDS; ++r) {
    fused_c<<<(C_N + 15) / 16, 256, 0, stream>>>(h_var_bf, rs_c, src_c,
                                                 W_v2c, b_v2c, W_c2v, h_con, t_bf);
    if (r < ROUNDS - 1) {
      gather_v_k<0><<<(V_N + 15) / 16, 256, 0, stream>>>(t_bf, rs_v, src_v, b_c2v, h_var,
                                                         h_var_bf, nullptr, nullptr, nullptr);
    } else {
      gather_v_k<1><<<(V_N + 15) / 16, 256, 0, stream>>>(t_bf, rs_v, src_v, b_c2v, h_var,
                                                         nullptr, W_score, b_score, out);
    }
  }
}

// Round 6
// 333.526 us; speedup vs baseline: 2.4933x; 1.3488x over previous
//
#include <hip/hip_runtime.h>

typedef unsigned short u16;
typedef unsigned int u32;

#define V_N 100000
#define C_N 50000
#define E_N 1250000
#define VF_N 32
#define H_N 64
#define ROUNDS 3

#define TILE 4096
#define NT ((E_N + TILE - 1) / TILE)      // 306 edge tiles
#define NB_C ((C_N + 127) / 128)          // 391 coarse buckets (128 dests each)
#define NB_V ((V_N + 255) / 256)          // 391 coarse buckets (256 dests each)
#define FC_BLOCKS 1280                    // 5 blocks/CU (32KB LDS each) persistent

static __device__ __forceinline__ float bf2f(u16 x) {
  return __uint_as_float(((u32)x) << 16);
}
static __device__ __forceinline__ u16 f2bf(float f) {
  u32 u = __float_as_uint(f);
  u32 r = (u + 0x7fff + ((u >> 16) & 1)) >> 16;  // RNE
  return (u16)r;
}

// ---------------- CSR build: two-level bucket sort, block-aggregated atomics ----

__global__ __launch_bounds__(256) void bucket_hist(const int* __restrict__ vi,
                                                   const int* __restrict__ ci,
                                                   int* __restrict__ gh_c,
                                                   int* __restrict__ gh_v) {
  __shared__ int hc[NB_C], hv[NB_V];
  int t = threadIdx.x;
  for (int j = t; j < NB_C; j += 256) hc[j] = 0;
  for (int j = t; j < NB_V; j += 256) hv[j] = 0;
  __syncthreads();
  int base = blockIdx.x * TILE;
#pragma unroll
  for (int i = 0; i < 16; ++i) {
    int idx = base + i * 256 + t;
    if (idx < E_N) {
      atomicAdd(&hc[ci[idx] >> 7], 1);
      atomicAdd(&hv[vi[idx] >> 8], 1);
    }
  }
  __syncthreads();
  for (int j = t; j < NB_C; j += 256) if (hc[j]) atomicAdd(&gh_c[j], hc[j]);
  for (int j = t; j < NB_V; j += 256) if (hv[j]) atomicAdd(&gh_v[j], hv[j]);
}

__global__ __launch_bounds__(512) void bucket_scan(const int* __restrict__ gh_c,
                                                   const int* __restrict__ gh_v,
                                                   int* __restrict__ base_c,
                                                   int* __restrict__ cursor_c,
                                                   int* __restrict__ base_v,
                                                   int* __restrict__ cursor_v,
                                                   int* __restrict__ rs_c,
                                                   int* __restrict__ rs_v) {
  __shared__ int lds[512];
  int t = threadIdx.x;
  int x = (t < NB_C) ? gh_c[t] : 0;
  lds[t] = x;
  __syncthreads();
  for (int off = 1; off < 512; off <<= 1) {
    int v = (t >= off) ? lds[t - off] : 0;
    __syncthreads();
    lds[t] += v;
    __syncthreads();
  }
  int excl = lds[t] - x;
  if (t < NB_C) { base_c[t] = excl; cursor_c[t] = excl; }
  if (t == 511) base_c[NB_C] = lds[511];
  __syncthreads();
  int y = (t < NB_V) ? gh_v[t] : 0;
  lds[t] = y;
  __syncthreads();
  for (int off = 1; off < 512; off <<= 1) {
    int v = (t >= off) ? lds[t - off] : 0;
    __syncthreads();
    lds[t] += v;
    __syncthreads();
  }
  int excl2 = lds[t] - y;
  if (t < NB_V) { base_v[t] = excl2; cursor_v[t] = excl2; }
  if (t == 511) base_v[NB_V] = lds[511];
  if (t == 0) { rs_c[C_N] = E_N; rs_v[V_N] = E_N; }
}

// Packed element: (local_dest << 17) | src_id   (src < 2^17, local_dest <= 255)
__global__ __launch_bounds__(256) void scatter_pack(const int* __restrict__ vi,
                                                    const int* __restrict__ ci,
                                                    int* __restrict__ cursor_c,
                                                    int* __restrict__ cursor_v,
                                                    int* __restrict__ packed_c,
                                                    int* __restrict__ packed_v) {
  __shared__ int hc[NB_C], hv[NB_V], sc[NB_C], sv[NB_V];
  int t = threadIdx.x;
  for (int j = t; j < NB_C; j += 256) hc[j] = 0;
  for (int j = t; j < NB_V; j += 256) hv[j] = 0;
  __syncthreads();
  int base = blockIdx.x * TILE;
  int cc[16], vv[16];
#pragma unroll
  for (int i = 0; i < 16; ++i) {
    int idx = base + i * 256 + t;
    if (idx < E_N) {
      cc[i] = ci[idx];
      vv[i] = vi[idx];
      atomicAdd(&hc[cc[i] >> 7], 1);
      atomicAdd(&hv[vv[i] >> 8], 1);
    } else {
      cc[i] = -1;
      vv[i] = -1;
    }
  }
  __syncthreads();
  for (int j = t; j < NB_C; j += 256) {
    int n = hc[j];
    if (n > 0) sc[j] = atomicAdd(&cursor_c[j], n);
    hc[j] = 0;
  }
  for (int j = t; j < NB_V; j += 256) {
    int n = hv[j];
    if (n > 0) sv[j] = atomicAdd(&cursor_v[j], n);
    hv[j] = 0;
  }
  __syncthreads();
#pragma unroll
  for (int i = 0; i < 16; ++i) {
    if (cc[i] >= 0) {
      int b = cc[i] >> 7;
      int r = atomicAdd(&hc[b], 1);
      packed_c[sc[b] + r] = ((cc[i] & 127) << 17) | vv[i];
      int b2 = vv[i] >> 8;
      int r2 = atomicAdd(&hv[b2], 1);
      packed_v[sv[b2] + r2] = ((vv[i] & 255) << 17) | cc[i];
    }
  }
}

template <int LOCAL_N, int N_DEST>
__global__ __launch_bounds__(256) void fine_sort(const int* __restrict__ packed,
                                                 const int* __restrict__ base,
                                                 int* __restrict__ rs,
                                                 int* __restrict__ srco) {
  __shared__ int cnt[LOCAL_N];
  __shared__ int excl[LOCAL_N];
  int b = blockIdx.x, t = threadIdx.x;
  int s0 = base[b], s1 = base[b + 1];
  if (t < LOCAL_N) cnt[t] = 0;
  __syncthreads();
  for (int i = s0 + t; i < s1; i += 256) atomicAdd(&cnt[packed[i] >> 17], 1);
  __syncthreads();
  if (t == 0) {
    int run = 0;
    for (int k = 0; k < LOCAL_N; ++k) { excl[k] = run; run += cnt[k]; }
  }
  __syncthreads();
  if (t < LOCAL_N) {
    int d = b * LOCAL_N + t;
    if (d < N_DEST) rs[d] = s0 + excl[t];
    cnt[t] = excl[t];
  }
  __syncthreads();
  for (int i = s0 + t; i < s1; i += 256) {
    int w = packed[i];
    int ld = w >> 17;
    int pos = s0 + atomicAdd(&cnt[ld], 1);
    srco[pos] = w & 0x1FFFF;
  }
}

// ---------------- input MLP: h = relu(feat[n,32] @ W[32,64] + b) ----------------

template <int WRITE_BF>
__global__ __launch_bounds__(256) void init_mlp(const float* __restrict__ feat,
                                                const float* __restrict__ W,
                                                const float* __restrict__ b,
                                                float* __restrict__ h,
                                                u16* __restrict__ hbf, int n) {
  __shared__ float Wl[VF_N * H_N];
  for (int i = threadIdx.x; i < VF_N * H_N; i += 256) Wl[i] = W[i];
  __syncthreads();
  int g = (blockIdx.x * 256 + threadIdx.x) >> 4;
  int lane = threadIdx.x & 15;
  if (g >= n) return;
  float2 rv = *(const float2*)&feat[(size_t)g * VF_N + lane * 2];
  float4 acc = *(const float4*)&b[lane * 4];
#pragma unroll
  for (int k = 0; k < VF_N; ++k) {
    float el = (k & 1) ? rv.y : rv.x;
    float v = __shfl(el, k >> 1, 16);
    float4 w = *(const float4*)&Wl[k * H_N + lane * 4];
    acc.x += v * w.x; acc.y += v * w.y; acc.z += v * w.z; acc.w += v * w.w;
  }
  acc.x = fmaxf(acc.x, 0.f); acc.y = fmaxf(acc.y, 0.f);
  acc.z = fmaxf(acc.z, 0.f); acc.w = fmaxf(acc.w, 0.f);
  *(float4*)&h[(size_t)g * H_N + lane * 4] = acc;
  if (WRITE_BF) {
    ushort4 q;
    q.x = f2bf(acc.x); q.y = f2bf(acc.y); q.z = f2bf(acc.z); q.w = f2bf(acc.w);
    *(ushort4*)&hbf[(size_t)g * H_N + lane * 4] = q;
  }
}

// ---------------- batched bf16 row gather: 16 independent loads in flight ------

static __device__ __forceinline__ void gather_rows_bf16(const u16* __restrict__ tbl,
                                                        const int* __restrict__ src,
                                                        int s, int e, int lane,
                                                        float4& acc) {
  int p = s;
  // full 16-batches: unpredicated, 16 outstanding loads
  for (; p + 16 <= e; p += 16) {
    int myidx = src[p + lane];
    ushort4 vv[16];
#pragma unroll
    for (int j = 0; j < 16; ++j) {
      int sj = __shfl(myidx, j, 16);
      vv[j] = *(const ushort4*)&tbl[(size_t)sj * H_N + lane * 4];
    }
#pragma unroll
    for (int j = 0; j < 16; ++j) {
      acc.x += bf2f(vv[j].x); acc.y += bf2f(vv[j].y);
      acc.z += bf2f(vv[j].z); acc.w += bf2f(vv[j].w);
    }
  }
  // predicated tail batch (lanes >= cnt load row 0 -> broadcast, cheap)
  if (p < e) {
    int cnt = e - p;
    int myidx = (lane < cnt) ? src[p + lane] : 0;
    ushort4 vv[16];
#pragma unroll
    for (int j = 0; j < 16; ++j) {
      int sj = __shfl(myidx, j, 16);
      vv[j] = *(const ushort4*)&tbl[(size_t)sj * H_N + lane * 4];
    }
#pragma unroll
    for (int j = 0; j < 16; ++j) {
      if (j < cnt) {
        acc.x += bf2f(vv[j].x); acc.y += bf2f(vv[j].y);
        acc.z += bf2f(vv[j].z); acc.w += bf2f(vv[j].w);
      }
    }
  }
}

// ---------------- fused C-side update (persistent) ----------------
//   s      = segsum_c(h_var_bf)              (bf16 gather, fp32 accumulate)
//   h_con  = relu(h_con + s @ W_v2c + b_v2c)
//   t_bf   = bf16(h_con @ W_c2v)             (payload for the V-side gather)

__global__ __launch_bounds__(256) void fused_c(const u16* __restrict__ h_var_bf,
                                               const int* __restrict__ rs,
                                               const int* __restrict__ src,
                                               const float* __restrict__ W1g,
                                               const float* __restrict__ b1g,
                                               const float* __restrict__ W2g,
                                               float* __restrict__ h_con,
                                               u16* __restrict__ t_out) {
  __shared__ float W1[H_N * H_N];
  __shared__ float W2[H_N * H_N];
  for (int i = threadIdx.x; i < H_N * H_N; i += 256) { W1[i] = W1g[i]; W2[i] = W2g[i]; }
  __syncthreads();
  int lane = threadIdx.x & 15;
  int grp = threadIdx.x >> 4;  // 0..15 dest-groups per block
  // persistent grid-stride over dest groups; no barriers inside -> divergence ok
  for (int g0 = blockIdx.x * 16; g0 < C_N; g0 += FC_BLOCKS * 16) {
    int g = g0 + grp;
    if (g >= C_N) continue;
    int s = rs[g], e = rs[g + 1];
    float4 acc = {0.f, 0.f, 0.f, 0.f};
    gather_rows_bf16(h_var_bf, src, s, e, lane, acc);
    // m = acc @ W1
    float4 m = {0.f, 0.f, 0.f, 0.f};
#pragma unroll
    for (int k = 0; k < H_N; ++k) {
      int sel = k & 3;
      float el = (sel == 0) ? acc.x : (sel == 1) ? acc.y : (sel == 2) ? acc.z : acc.w;
      float v = __shfl(el, k >> 2, 16);
      float4 w = *(const float4*)&W1[k * H_N + lane * 4];
      m.x += v * w.x; m.y += v * w.y; m.z += v * w.z; m.w += v * w.w;
    }
    float4 hv = *(const float4*)&h_con[(size_t)g * H_N + lane * 4];
    float4 b4 = *(const float4*)&b1g[lane * 4];
    float4 hn;
    hn.x = fmaxf(hv.x + m.x + b4.x, 0.f);
    hn.y = fmaxf(hv.y + m.y + b4.y, 0.f);
    hn.z = fmaxf(hv.z + m.z + b4.z, 0.f);
    hn.w = fmaxf(hv.w + m.w + b4.w, 0.f);
    *(float4*)&h_con[(size_t)g * H_N + lane * 4] = hn;
    // t = hn @ W2 -> bf16
    float4 tt = {0.f, 0.f, 0.f, 0.f};
#pragma unroll
    for (int k = 0; k < H_N; ++k) {
      int sel = k & 3;
      float el = (sel == 0) ? hn.x : (sel == 1) ? hn.y : (sel == 2) ? hn.z : hn.w;
      float v = __shfl(el, k >> 2, 16);
      float4 w = *(const float4*)&W2[k * H_N + lane * 4];
      tt.x += v * w.x; tt.y += v * w.y; tt.z += v * w.z; tt.w += v * w.w;
    }
    ushort4 q;
    q.x = f2bf(tt.x); q.y = f2bf(tt.y); q.z = f2bf(tt.z); q.w = f2bf(tt.w);
    *(ushort4*)&t_out[(size_t)g * H_N + lane * 4] = q;
  }
}

// ---------------- V-side gather (+ fused score epilogue on last round) ----------

template <int DO_SCORE>
__global__ __launch_bounds__(256) void gather_v_k(const u16* __restrict__ t,
                                                  const int* __restrict__ rs,
                                                  const int* __restrict__ src,
                                                  const float* __restrict__ bias,
                                                  float* __restrict__ h,
                                                  u16* __restrict__ hbf,
                                                  const float* __restrict__ Ws,
                                                  const float* __restrict__ bs,
                                                  float* __restrict__ out) {
  int g = (blockIdx.x * 256 + threadIdx.x) >> 4;
  int lane = threadIdx.x & 15;
  if (g >= V_N) return;
  int s = rs[g], e = rs[g + 1];
  float4 acc = {0.f, 0.f, 0.f, 0.f};
  gather_rows_bf16(t, src, s, e, lane, acc);
  float4 hv = *(const float4*)&h[(size_t)g * H_N + lane * 4];
  float4 b4 = *(const float4*)&bias[lane * 4];
  float4 hn;
  hn.x = fmaxf(hv.x + acc.x + b4.x, 0.f);
  hn.y = fmaxf(hv.y + acc.y + b4.y, 0.f);
  hn.z = fmaxf(hv.z + acc.z + b4.z, 0.f);
  hn.w = fmaxf(hv.w + acc.w + b4.w, 0.f);
  if (DO_SCORE) {
    float4 w = *(const float4*)&Ws[lane * 4];
    float d = hn.x * w.x + hn.y * w.y + hn.z * w.z + hn.w * w.w;
    d += __shfl_down(d, 8, 16);
    d += __shfl_down(d, 4, 16);
    d += __shfl_down(d, 2, 16);
    d += __shfl_down(d, 1, 16);
    if (lane == 0) out[g] = d + bs[0];
  } else {
    *(float4*)&h[(size_t)g * H_N + lane * 4] = hn;
    ushort4 q;
    q.x = f2bf(hn.x); q.y = f2bf(hn.y); q.z = f2bf(hn.z); q.w = f2bf(hn.w);
    *(ushort4*)&hbf[(size_t)g * H_N + lane * 4] = q;
  }
}

// ---------------- launch ----------------

extern "C" void kernel_launch(void* const* d_in, const int* in_sizes, int n_in,
                              void* d_out, int out_size, void* d_ws, size_t ws_size,
                              hipStream_t stream) {
  const float* var_feat = (const float*)d_in[0];
  const float* con_feat = (const float*)d_in[1];
  const float* W_var = (const float*)d_in[2];
  const float* b_var = (const float*)d_in[3];
  const float* W_con = (const float*)d_in[4];
  const float* b_con = (const float*)d_in[5];
  const float* W_v2c = (const float*)d_in[6];
  const float* b_v2c = (const float*)d_in[7];
  const float* W_c2v = (const float*)d_in[8];
  const float* b_c2v = (const float*)d_in[9];
  const float* W_score = (const float*)d_in[10];
  const float* b_score = (const float*)d_in[11];
  const int* var_idx = (const int*)d_in[12];
  const int* constr_idx = (const int*)d_in[13];
  float* out = (float*)d_out;

  char* p = (char*)d_ws;
  auto alloc = [&](size_t bytes) {
    char* r = p;
    p += (bytes + 255) & ~(size_t)255;
    return r;
  };
  float* h_var = (float*)alloc((size_t)V_N * H_N * 4);
  u16* h_var_bf = (u16*)alloc((size_t)V_N * H_N * 2);
  float* h_con = (float*)alloc((size_t)C_N * H_N * 4);
  u16* t_bf = (u16*)alloc((size_t)C_N * H_N * 2);
  int* rs_c = (int*)alloc((size_t)(C_N + 1) * 4);
  int* rs_v = (int*)alloc((size_t)(V_N + 1) * 4);
  int* src_c = (int*)alloc((size_t)E_N * 4);
  int* src_v = (int*)alloc((size_t)E_N * 4);
  int* packed_c = (int*)alloc((size_t)E_N * 4);
  int* packed_v = (int*)alloc((size_t)E_N * 4);
  int* ghist_c = (int*)alloc((size_t)NB_C * 4);
  int* ghist_v = (int*)alloc((size_t)NB_V * 4);
  int* base_c = (int*)alloc((size_t)(NB_C + 1) * 4);
  int* base_v = (int*)alloc((size_t)(NB_V + 1) * 4);
  int* cursor_c = (int*)alloc((size_t)NB_C * 4);
  int* cursor_v = (int*)alloc((size_t)NB_V * 4);

  hipMemsetAsync(ghist_c, 0, (size_t)NB_C * 4, stream);
  hipMemsetAsync(ghist_v, 0, (size_t)NB_V * 4, stream);

  bucket_hist<<<NT, 256, 0, stream>>>(var_idx, constr_idx, ghist_c, ghist_v);
  bucket_scan<<<1, 512, 0, stream>>>(ghist_c, ghist_v, base_c, cursor_c,
                                     base_v, cursor_v, rs_c, rs_v);
  scatter_pack<<<NT, 256, 0, stream>>>(var_idx, constr_idx, cursor_c, cursor_v,
                                       packed_c, packed_v);
  fine_sort<128, C_N><<<NB_C, 256, 0, stream>>>(packed_c, base_c, rs_c, src_c);
  fine_sort<256, V_N><<<NB_V, 256, 0, stream>>>(packed_v, base_v, rs_v, src_v);

  init_mlp<1><<<(V_N + 15) / 16, 256, 0, stream>>>(var_feat, W_var, b_var, h_var, h_var_bf, V_N);
  init_mlp<0><<<(C_N + 15) / 16, 256, 0, stream>>>(con_feat, W_con, b_con, h_con, nullptr, C_N);

  for (int r = 0; r < ROUNDS; ++r) {
    fused_c<<<FC_BLOCKS, 256, 0, stream>>>(h_var_bf, rs_c, src_c,
                                           W_v2c, b_v2c, W_c2v, h_con, t_bf);
    if (r < ROUNDS - 1) {
      gather_v_k<0><<<(V_N + 15) / 16, 256, 0, stream>>>(t_bf, rs_v, src_v, b_c2v, h_var,
                                                         h_var_bf, nullptr, nullptr, nullptr);
    } else {
      gather_v_k<1><<<(V_N + 15) / 16, 256, 0, stream>>>(t_bf, rs_v, src_v, b_c2v, h_var,
                                                         nullptr, W_score, b_score, out);
    }
  }
}